// Round 1
// baseline (470.460 us; speedup 1.0000x reference)
//
#include <hip/hip_runtime.h>
#include <math.h>

#define IMG 800.0f
#define SCORE_TH 0.25f
#define NMS_TH 0.5f
#define MAXDET 100
#define BBOX_CLIP 4.135166556742356f /* log(1000/16) */

constexpr int kB = 16;
constexpr int kN = 4000;
constexpr int kD = 1024;

// ---------------------------------------------------------------------------
// Kernel 1: fused head matmul (6 needed channels only) + softmax + box decode.
// One wave per row; per-lane weight slice held in registers (24 float4).
// Next-row feats prefetched so global loads are in flight during the
// shuffle-reduce + lane-0 epilogue tail of the current row.
// ---------------------------------------------------------------------------
__global__ __launch_bounds__(256, 2) void head_kernel(
    const float* __restrict__ feats, const float* __restrict__ proposals,
    const float* __restrict__ Wc, const float* __restrict__ bc,
    const float* __restrict__ Wb, const float* __restrict__ bb,
    float* __restrict__ out, float* __restrict__ ws_scores,
    float* __restrict__ ws_boxes) {
  const int lane = threadIdx.x & 63;
  const int waveId = (blockIdx.x * blockDim.x + threadIdx.x) >> 6;
  const int nWaves = (gridDim.x * blockDim.x) >> 6;

  const float4* Wc4 = (const float4*)Wc;  // (2,1024) -> 2*256 float4
  const float4* Wb4 = (const float4*)Wb;  // (8,1024) -> 8*256 float4
  float4 w0[4], w1[4], w4[4], w5[4], w6[4], w7[4];
#pragma unroll
  for (int ch = 0; ch < 4; ++ch) {
    int idx = ch * 64 + lane;
    w0[ch] = Wc4[0 * 256 + idx];
    w1[ch] = Wc4[1 * 256 + idx];
    w4[ch] = Wb4[4 * 256 + idx];
    w5[ch] = Wb4[5 * 256 + idx];
    w6[ch] = Wb4[6 * 256 + idx];
    w7[ch] = Wb4[7 * 256 + idx];
  }
  const float bc0 = bc[0], bc1 = bc[1];
  const float bb4 = bb[4], bb5 = bb[5], bb6 = bb[6], bb7 = bb[7];

  const int R = kB * kN;
  int row = waveId;
  float4 f[4];
  if (row < R) {
    const float4* F = (const float4*)(feats + (size_t)row * kD);
#pragma unroll
    for (int ch = 0; ch < 4; ++ch) f[ch] = F[ch * 64 + lane];
  }
  for (; row < R; row += nWaves) {
    // Prefetch next row before consuming the current one.
    float4 fn[4];
    const int nrow = row + nWaves;
    if (nrow < R) {
      const float4* Fn = (const float4*)(feats + (size_t)nrow * kD);
#pragma unroll
      for (int ch = 0; ch < 4; ++ch) fn[ch] = Fn[ch * 64 + lane];
    }

    float a0 = 0.f, a1 = 0.f, a4 = 0.f, a5 = 0.f, a6 = 0.f, a7 = 0.f;
#pragma unroll
    for (int ch = 0; ch < 4; ++ch) {
      float4 ff = f[ch];
      a0 = fmaf(ff.x, w0[ch].x, fmaf(ff.y, w0[ch].y, fmaf(ff.z, w0[ch].z, fmaf(ff.w, w0[ch].w, a0))));
      a1 = fmaf(ff.x, w1[ch].x, fmaf(ff.y, w1[ch].y, fmaf(ff.z, w1[ch].z, fmaf(ff.w, w1[ch].w, a1))));
      a4 = fmaf(ff.x, w4[ch].x, fmaf(ff.y, w4[ch].y, fmaf(ff.z, w4[ch].z, fmaf(ff.w, w4[ch].w, a4))));
      a5 = fmaf(ff.x, w5[ch].x, fmaf(ff.y, w5[ch].y, fmaf(ff.z, w5[ch].z, fmaf(ff.w, w5[ch].w, a5))));
      a6 = fmaf(ff.x, w6[ch].x, fmaf(ff.y, w6[ch].y, fmaf(ff.z, w6[ch].z, fmaf(ff.w, w6[ch].w, a6))));
      a7 = fmaf(ff.x, w7[ch].x, fmaf(ff.y, w7[ch].y, fmaf(ff.z, w7[ch].z, fmaf(ff.w, w7[ch].w, a7))));
    }
#pragma unroll
    for (int off = 32; off; off >>= 1) {
      a0 += __shfl_xor(a0, off);
      a1 += __shfl_xor(a1, off);
      a4 += __shfl_xor(a4, off);
      a5 += __shfl_xor(a5, off);
      a6 += __shfl_xor(a6, off);
      a7 += __shfl_xor(a7, off);
    }
    if (lane == 0) {
      float l0 = a0 + bc0, l1 = a1 + bc1;
      float score = 1.0f / (1.0f + __expf(l0 - l1));
      float sth = score > SCORE_TH ? score : 0.0f;

      float4 p = ((const float4*)proposals)[row];
      float w = p.z - p.x, h = p.w - p.y;
      float cx = p.x + 0.5f * w, cy = p.y + 0.5f * h;
      float dx = (a4 + bb4) * 0.1f;
      float dy = (a5 + bb5) * 0.1f;
      float dw = fminf((a6 + bb6) * 0.2f, BBOX_CLIP);
      float dh = fminf((a7 + bb7) * 0.2f, BBOX_CLIP);
      float pcx = fmaf(dx, w, cx), pcy = fmaf(dy, h, cy);
      float pw = __expf(dw) * w, ph = __expf(dh) * h;
      float x1 = fminf(fmaxf(pcx - 0.5f * pw, 0.f), IMG);
      float y1 = fminf(fmaxf(pcy - 0.5f * ph, 0.f), IMG);
      float x2 = fminf(fmaxf(pcx + 0.5f * pw, 0.f), IMG);
      float y2 = fminf(fmaxf(pcy + 0.5f * ph, 0.f), IMG);

      size_t ob = (size_t)row * 5;
      out[ob + 0] = x1;
      out[ob + 1] = y1;
      out[ob + 2] = x2;
      out[ob + 3] = y2;
      ws_scores[row] = sth;
      ((float4*)ws_boxes)[row] = make_float4(x1, y1, x2, y2);
    }
#pragma unroll
    for (int ch = 0; ch < 4; ++ch) f[ch] = fn[ch];
  }
}

// ---------------------------------------------------------------------------
// DPP-based wave argmax on packed u64 keys: VALU-latency cross-lane instead of
// ds_bpermute (~120 cy/stage). Zero-fill (bound_ctrl + old=0) is safe: all
// real keys are > 0, so a 0 candidate never wins.
// ---------------------------------------------------------------------------
template <int CTRL>
__device__ __forceinline__ unsigned long long dpp_max_u64(unsigned long long k) {
  int lo = __builtin_amdgcn_update_dpp(0, (int)(unsigned)k, CTRL, 0xF, 0xF, true);
  int hi =
      __builtin_amdgcn_update_dpp(0, (int)(unsigned)(k >> 32), CTRL, 0xF, 0xF, true);
  unsigned long long o = ((unsigned long long)(unsigned)hi << 32) | (unsigned)lo;
  return o > k ? o : k;
}

__device__ __forceinline__ unsigned long long wave_max_u64(unsigned long long k) {
  k = dpp_max_u64<0x121>(k);  // row_ror:1
  k = dpp_max_u64<0x122>(k);  // row_ror:2
  k = dpp_max_u64<0x124>(k);  // row_ror:4
  k = dpp_max_u64<0x128>(k);  // row_ror:8   (every lane: 16-lane row max)
  k = dpp_max_u64<0x142>(k);  // row_bcast15 (rows 1,3 pick up rows 0,2)
  k = dpp_max_u64<0x143>(k);  // row_bcast31 (lane 63: wave max)
  return k;
}

// ---------------------------------------------------------------------------
// Kernel 2: greedy NMS, one 1024-thread block (16 waves) per batch image.
// 4 slots/thread (was 16): per-iteration issue count for the IoU loop and the
// in-thread key pack/tree drops 4x; cross-wave reduce grows to 16 broadcast
// LDS keys + 15 u64 maxes (cheap). Key = (score_bits << 32) | ~n: max-key ==
// reference argmax with first-index tie-break; sentinels (khi=0, n>=4000)
// lose to all real rows; all-suppressed case picks row 0 with valid=false
// (keep-revocation exact). One barrier/iter, double-buffered leader keys.
// ---------------------------------------------------------------------------
constexpr int kNmsThreads = 1024;
constexpr int kSlots = 4;                      // 4*1024 = 4096 >= 4000
constexpr int kNmsWaves = kNmsThreads / 64;    // 16

__global__ __launch_bounds__(kNmsThreads, 1) void nms_kernel(
    const float* __restrict__ ws_scores, const float* __restrict__ ws_boxes,
    float* __restrict__ out) {
  const int b = blockIdx.x;
  const int t = threadIdx.x;  // 0..1023
  const int wave = t >> 6;
  const int lane = t & 63;

  __shared__ float4 Lbox[kN];  // 64000 B
  __shared__ unsigned long long Lkey[2][kNmsWaves];

  const float* sc = ws_scores + (size_t)b * kN;
  const float4* bx = (const float4*)ws_boxes + (size_t)b * kN;

  unsigned khi[kSlots];
  float areaE[kSlots];  // area + 1e-9
  float4 box[kSlots];
  unsigned keep_mask = 0u;
  const unsigned nt = ~(unsigned)t;  // ~(k*1024+t) = nt - k*1024

#pragma unroll
  for (int k = 0; k < kSlots; ++k) {
    int n = k * kNmsThreads + t;
    if (n < kN) {
      box[k] = bx[n];
      khi[k] = __float_as_uint(sc[n]);  // scores >= 0: bits monotone
      areaE[k] = fmaxf(box[k].z - box[k].x, 0.f) *
                     fmaxf(box[k].w - box[k].y, 0.f) +
                 1e-9f;
      Lbox[n] = box[k];
    } else {
      box[k] = make_float4(0.f, 0.f, 0.f, 0.f);  // inter==0 vs any real box
      khi[k] = 0u;
      areaE[k] = 1e-9f;
    }
  }

  auto reduce_publish = [&](int parity) {
    unsigned long long lk[kSlots];
#pragma unroll
    for (int k = 0; k < kSlots; ++k)
      lk[k] = ((unsigned long long)khi[k] << 32) |
              (unsigned long long)(nt - (unsigned)(k * kNmsThreads));
    lk[0] = lk[0] > lk[2] ? lk[0] : lk[2];
    lk[1] = lk[1] > lk[3] ? lk[1] : lk[3];
    lk[0] = lk[0] > lk[1] ? lk[0] : lk[1];
    unsigned long long wkey = wave_max_u64(lk[0]);
    if (lane == 63) Lkey[parity][wave] = wkey;
  };

  reduce_publish(1);  // loop it=0 reads parity (0+1)&1 = 1
  __syncthreads();

  for (int it = 0; it < MAXDET; ++it) {
    const int pr = (it + 1) & 1;
    // 16 leader keys, same-address broadcast reads (conflict-free).
    unsigned long long m[8];
#pragma unroll
    for (int i = 0; i < 8; ++i) {
      unsigned long long a = Lkey[pr][i], c = Lkey[pr][i + 8];
      m[i] = a > c ? a : c;
    }
#pragma unroll
    for (int i = 0; i < 4; ++i) m[i] = m[i] > m[i + 4] ? m[i] : m[i + 4];
    m[0] = m[0] > m[2] ? m[0] : m[2];
    m[1] = m[1] > m[3] ? m[1] : m[3];
    unsigned long long wk = m[0] > m[1] ? m[0] : m[1];
    // Uniform across the block -> scalarize the decode.
    const unsigned whi = (unsigned)__builtin_amdgcn_readfirstlane((int)(wk >> 32));
    const unsigned wlo = (unsigned)__builtin_amdgcn_readfirstlane((int)(unsigned)wk);
    const unsigned wn = ~wlo;  // winner row, always < kN when valid; 0 otherwise
    const bool valid = whi != 0u;
    const float4 wb = Lbox[wn];  // broadcast read
    const float wa = fmaxf(wb.z - wb.x, 0.f) * fmaxf(wb.w - wb.y, 0.f);
    const bool iOwn = ((unsigned)t == (wn & (unsigned)(kNmsThreads - 1)));
    const int oSlot = (int)(wn >> 10);
    if (iOwn) {
      unsigned bit = 1u << oSlot;
      keep_mask = valid ? (keep_mask | bit) : (keep_mask & ~bit);
    }
#pragma unroll
    for (int k = 0; k < kSlots; ++k) {
      float dx = fminf(wb.z, box[k].z) - fmaxf(wb.x, box[k].x);
      float dy = fminf(wb.w, box[k].w) - fmaxf(wb.y, box[k].y);
      float inter3 = 3.0f * fmaxf(dx, 0.f) * fmaxf(dy, 0.f);
      // iou > 0.5  <=>  3*inter > wa + area + 1e-9
      bool sup = inter3 > wa + areaE[k];
      if (sup || (iOwn && k == oSlot)) khi[k] = 0u;
    }
    reduce_publish(it & 1);
    __syncthreads();
  }

#pragma unroll
  for (int k = 0; k < kSlots; ++k) {
    int n = k * kNmsThreads + t;
    if (n < kN) {
      // ws_scores untouched by this kernel: re-read instead of keeping orig[]
      out[((size_t)(b * kN + n)) * 5 + 4] =
          (keep_mask >> k) & 1u ? sc[n] : 0.0f;
    }
  }
}

extern "C" void kernel_launch(void* const* d_in, const int* in_sizes, int n_in,
                              void* d_out, int out_size, void* d_ws,
                              size_t ws_size, hipStream_t stream) {
  const float* feats = (const float*)d_in[0];      // (16,4000,1024)
  const float* proposals = (const float*)d_in[1];  // (16,4000,4)
  const float* Wc = (const float*)d_in[2];         // (2,1024)
  const float* bc = (const float*)d_in[3];         // (2,)
  const float* Wb = (const float*)d_in[4];         // (8,1024)
  const float* bb = (const float*)d_in[5];         // (8,)
  float* out = (float*)d_out;                      // (16,4000,5)

  float* ws_scores = (float*)d_ws;        // 64000 floats
  float* ws_boxes = ws_scores + kB * kN;  // 64000*4 floats, 16B aligned

  head_kernel<<<512, 256, 0, stream>>>(feats, proposals, Wc, bc, Wb, bb, out,
                                       ws_scores, ws_boxes);
  nms_kernel<<<kB, kNmsThreads, 0, stream>>>(ws_scores, ws_boxes, out);
}

// Round 2
// 446.153 us; speedup vs baseline: 1.0545x; 1.0545x over previous
//
#include <hip/hip_runtime.h>
#include <math.h>

#define IMG 800.0f
#define SCORE_TH 0.25f
#define NMS_TH 0.5f
#define MAXDET 100
#define BBOX_CLIP 4.135166556742356f /* log(1000/16) */

constexpr int kB = 16;
constexpr int kN = 4000;
constexpr int kD = 1024;

// ---------------------------------------------------------------------------
// Kernel 1: fused head matmul (6 needed channels only) + softmax + box decode.
// One wave per row; per-lane weight slice held in registers (24 float4).
// BW-bound: 262 MB feats at ~6.5 TB/s ~= 40 us floor; 2 waves/SIMD already
// deliver ~23 B/cy/CU issue capacity vs the 10.25 B/cy/CU HBM floor, so no
// prefetch/occupancy games needed (verified: prefetch variant was not faster).
// ---------------------------------------------------------------------------
__global__ __launch_bounds__(256, 2) void head_kernel(
    const float* __restrict__ feats, const float* __restrict__ proposals,
    const float* __restrict__ Wc, const float* __restrict__ bc,
    const float* __restrict__ Wb, const float* __restrict__ bb,
    float* __restrict__ out, float* __restrict__ ws_scores,
    float* __restrict__ ws_boxes) {
  const int lane = threadIdx.x & 63;
  const int waveId = (blockIdx.x * blockDim.x + threadIdx.x) >> 6;
  const int nWaves = (gridDim.x * blockDim.x) >> 6;

  const float4* Wc4 = (const float4*)Wc;  // (2,1024) -> 2*256 float4
  const float4* Wb4 = (const float4*)Wb;  // (8,1024) -> 8*256 float4
  float4 w0[4], w1[4], w4[4], w5[4], w6[4], w7[4];
#pragma unroll
  for (int ch = 0; ch < 4; ++ch) {
    int idx = ch * 64 + lane;
    w0[ch] = Wc4[0 * 256 + idx];
    w1[ch] = Wc4[1 * 256 + idx];
    w4[ch] = Wb4[4 * 256 + idx];
    w5[ch] = Wb4[5 * 256 + idx];
    w6[ch] = Wb4[6 * 256 + idx];
    w7[ch] = Wb4[7 * 256 + idx];
  }
  const float bc0 = bc[0], bc1 = bc[1];
  const float bb4 = bb[4], bb5 = bb[5], bb6 = bb[6], bb7 = bb[7];

  const int R = kB * kN;
  for (int row = waveId; row < R; row += nWaves) {
    const float4* F = (const float4*)(feats + (size_t)row * kD);
    float a0 = 0.f, a1 = 0.f, a4 = 0.f, a5 = 0.f, a6 = 0.f, a7 = 0.f;
#pragma unroll
    for (int ch = 0; ch < 4; ++ch) {
      float4 f = F[ch * 64 + lane];
      a0 = fmaf(f.x, w0[ch].x, fmaf(f.y, w0[ch].y, fmaf(f.z, w0[ch].z, fmaf(f.w, w0[ch].w, a0))));
      a1 = fmaf(f.x, w1[ch].x, fmaf(f.y, w1[ch].y, fmaf(f.z, w1[ch].z, fmaf(f.w, w1[ch].w, a1))));
      a4 = fmaf(f.x, w4[ch].x, fmaf(f.y, w4[ch].y, fmaf(f.z, w4[ch].z, fmaf(f.w, w4[ch].w, a4))));
      a5 = fmaf(f.x, w5[ch].x, fmaf(f.y, w5[ch].y, fmaf(f.z, w5[ch].z, fmaf(f.w, w5[ch].w, a5))));
      a6 = fmaf(f.x, w6[ch].x, fmaf(f.y, w6[ch].y, fmaf(f.z, w6[ch].z, fmaf(f.w, w6[ch].w, a6))));
      a7 = fmaf(f.x, w7[ch].x, fmaf(f.y, w7[ch].y, fmaf(f.z, w7[ch].z, fmaf(f.w, w7[ch].w, a7))));
    }
#pragma unroll
    for (int off = 32; off; off >>= 1) {
      a0 += __shfl_xor(a0, off);
      a1 += __shfl_xor(a1, off);
      a4 += __shfl_xor(a4, off);
      a5 += __shfl_xor(a5, off);
      a6 += __shfl_xor(a6, off);
      a7 += __shfl_xor(a7, off);
    }
    if (lane == 0) {
      float l0 = a0 + bc0, l1 = a1 + bc1;
      float score = 1.0f / (1.0f + __expf(l0 - l1));
      float sth = score > SCORE_TH ? score : 0.0f;

      float4 p = ((const float4*)proposals)[row];
      float w = p.z - p.x, h = p.w - p.y;
      float cx = p.x + 0.5f * w, cy = p.y + 0.5f * h;
      float dx = (a4 + bb4) * 0.1f;
      float dy = (a5 + bb5) * 0.1f;
      float dw = fminf((a6 + bb6) * 0.2f, BBOX_CLIP);
      float dh = fminf((a7 + bb7) * 0.2f, BBOX_CLIP);
      float pcx = fmaf(dx, w, cx), pcy = fmaf(dy, h, cy);
      float pw = __expf(dw) * w, ph = __expf(dh) * h;
      float x1 = fminf(fmaxf(pcx - 0.5f * pw, 0.f), IMG);
      float y1 = fminf(fmaxf(pcy - 0.5f * ph, 0.f), IMG);
      float x2 = fminf(fmaxf(pcx + 0.5f * pw, 0.f), IMG);
      float y2 = fminf(fmaxf(pcy + 0.5f * ph, 0.f), IMG);

      size_t ob = (size_t)row * 5;
      out[ob + 0] = x1;
      out[ob + 1] = y1;
      out[ob + 2] = x2;
      out[ob + 3] = y2;
      ws_scores[row] = sth;
      ((float4*)ws_boxes)[row] = make_float4(x1, y1, x2, y2);
    }
  }
}

// ---------------------------------------------------------------------------
// DPP-based wave argmax on packed u64 keys: VALU-latency cross-lane instead of
// ds_bpermute (~120 cy/stage). Zero-fill (bound_ctrl + old=0) is safe: all
// real keys are > 0, so a 0 candidate never wins.
// ---------------------------------------------------------------------------
template <int CTRL>
__device__ __forceinline__ unsigned long long dpp_max_u64(unsigned long long k) {
  int lo = __builtin_amdgcn_update_dpp(0, (int)(unsigned)k, CTRL, 0xF, 0xF, true);
  int hi =
      __builtin_amdgcn_update_dpp(0, (int)(unsigned)(k >> 32), CTRL, 0xF, 0xF, true);
  unsigned long long o = ((unsigned long long)(unsigned)hi << 32) | (unsigned)lo;
  return o > k ? o : k;
}

__device__ __forceinline__ unsigned long long wave_max_u64(unsigned long long k) {
  k = dpp_max_u64<0x121>(k);  // row_ror:1
  k = dpp_max_u64<0x122>(k);  // row_ror:2
  k = dpp_max_u64<0x124>(k);  // row_ror:4
  k = dpp_max_u64<0x128>(k);  // row_ror:8   (every lane: 16-lane row max)
  k = dpp_max_u64<0x142>(k);  // row_bcast15 (rows 1,3 pick up rows 0,2)
  k = dpp_max_u64<0x143>(k);  // row_bcast31 (lane 63: wave max)
  return k;
}

// ---------------------------------------------------------------------------
// Kernel 2: greedy NMS, one 256-thread block (4 waves) per batch image.
// 4 waves = 1 wave/SIMD is the per-SIMD-issue sweet spot: the IoU work per
// SIMD is invariant under thread-count changes (measured: 1024-thread variant
// regressed +23 us from 4x the DPP chains + wider key tree + 16-wave barrier).
// State per thread (row n = k*256 + t): khi[16] = score bits (suppress -> 0),
// box[16], areaE[16]. Key = (khi << 32) | ~n: max-key == reference argmax with
// first-index tie-break; sentinels (khi=0, n>=4000) lose to all real rows;
// all-suppressed case picks row 0 with valid=false (keep-revocation exact).
// One barrier/iter, double-buffered 4-wave leader keys in LDS.
// ---------------------------------------------------------------------------
__global__ __launch_bounds__(256, 1) void nms_kernel(
    const float* __restrict__ ws_scores, const float* __restrict__ ws_boxes,
    float* __restrict__ out) {
  const int b = blockIdx.x;
  const int t = threadIdx.x;  // 0..255
  const int wave = t >> 6;
  const int lane = t & 63;

  __shared__ float4 Lbox[kN];  // 64000 B
  alignas(16) __shared__ unsigned long long Lkey[2][4];

  const float* sc = ws_scores + (size_t)b * kN;
  const float4* bx = (const float4*)ws_boxes + (size_t)b * kN;

  unsigned khi[16];
  float areaE[16];  // area + 1e-9
  float4 box[16];
  unsigned keep_mask = 0u;
  const unsigned nt = ~(unsigned)t;  // ~(0*256+t); slot k low word = nt - 256k

#pragma unroll
  for (int k = 0; k < 16; ++k) {
    int n = k * 256 + t;
    if (n < kN) {
      box[k] = bx[n];
      khi[k] = __float_as_uint(sc[n]);  // scores >= 0: bits monotone
      areaE[k] = fmaxf(box[k].z - box[k].x, 0.f) *
                     fmaxf(box[k].w - box[k].y, 0.f) +
                 1e-9f;
      Lbox[n] = box[k];
    } else {
      box[k] = make_float4(0.f, 0.f, 0.f, 0.f);  // inter==0 vs any real box
      khi[k] = 0u;
      areaE[k] = 1e-9f;
    }
  }

  auto reduce_publish = [&](int parity) {
    unsigned long long lk[16];
#pragma unroll
    for (int k = 0; k < 16; ++k)
      lk[k] = ((unsigned long long)khi[k] << 32) |
              (unsigned long long)(nt - (unsigned)(k * 256));
#pragma unroll
    for (int k = 0; k < 8; ++k) lk[k] = lk[k] > lk[k + 8] ? lk[k] : lk[k + 8];
#pragma unroll
    for (int k = 0; k < 4; ++k) lk[k] = lk[k] > lk[k + 4] ? lk[k] : lk[k + 4];
    lk[0] = lk[0] > lk[2] ? lk[0] : lk[2];
    lk[1] = lk[1] > lk[3] ? lk[1] : lk[3];
    lk[0] = lk[0] > lk[1] ? lk[0] : lk[1];
    unsigned long long wkey = wave_max_u64(lk[0]);
    if (lane == 63) Lkey[parity][wave] = wkey;
  };

  reduce_publish(1);  // loop it=0 reads parity (0+1)&1 = 1
  __syncthreads();

  for (int it = 0; it < MAXDET; ++it) {
    const int pr = (it + 1) & 1;
    // 4 leader keys as 2x ds_read_b128 (16B-aligned), broadcast (conflict-free)
    const ulonglong2* Lk2 = (const ulonglong2*)(&Lkey[pr][0]);
    ulonglong2 p01 = Lk2[0];
    ulonglong2 p23 = Lk2[1];
    unsigned long long wk = p01.x > p01.y ? p01.x : p01.y;
    unsigned long long k2 = p23.x > p23.y ? p23.x : p23.y;
    wk = wk > k2 ? wk : k2;
    // Uniform across the block -> scalarize the decode.
    const unsigned whi = (unsigned)__builtin_amdgcn_readfirstlane((int)(wk >> 32));
    const unsigned wlo = (unsigned)__builtin_amdgcn_readfirstlane((int)(unsigned)wk);
    const unsigned wn = ~wlo;  // winner row, always < kN
    const bool valid = whi != 0u;
    const float4 wb = Lbox[wn];  // broadcast read
    const float wa = fmaxf(wb.z - wb.x, 0.f) * fmaxf(wb.w - wb.y, 0.f);
    const bool iOwn = ((unsigned)t == (wn & 255u));
    const int oSlot = (int)(wn >> 8);
    if (iOwn) {
      unsigned bit = 1u << oSlot;
      keep_mask = valid ? (keep_mask | bit) : (keep_mask & ~bit);
    }
#pragma unroll
    for (int k = 0; k < 16; ++k) {
      float dx = fminf(wb.z, box[k].z) - fmaxf(wb.x, box[k].x);
      float dy = fminf(wb.w, box[k].w) - fmaxf(wb.y, box[k].y);
      float inter3 = 3.0f * fmaxf(dx, 0.f) * fmaxf(dy, 0.f);
      // iou > 0.5  <=>  3*inter > wa + area + 1e-9
      bool sup = inter3 > wa + areaE[k];
      if (sup || (iOwn && k == oSlot)) khi[k] = 0u;
    }
    reduce_publish(it & 1);
    __syncthreads();
  }

#pragma unroll
  for (int k = 0; k < 16; ++k) {
    int n = k * 256 + t;
    if (n < kN) {
      // ws_scores untouched by this kernel: re-read instead of keeping orig[]
      out[((size_t)(b * kN + n)) * 5 + 4] =
          (keep_mask >> k) & 1u ? sc[n] : 0.0f;
    }
  }
}

extern "C" void kernel_launch(void* const* d_in, const int* in_sizes, int n_in,
                              void* d_out, int out_size, void* d_ws,
                              size_t ws_size, hipStream_t stream) {
  const float* feats = (const float*)d_in[0];      // (16,4000,1024)
  const float* proposals = (const float*)d_in[1];  // (16,4000,4)
  const float* Wc = (const float*)d_in[2];         // (2,1024)
  const float* bc = (const float*)d_in[3];         // (2,)
  const float* Wb = (const float*)d_in[4];         // (8,1024)
  const float* bb = (const float*)d_in[5];         // (8,)
  float* out = (float*)d_out;                      // (16,4000,5)

  float* ws_scores = (float*)d_ws;        // 64000 floats
  float* ws_boxes = ws_scores + kB * kN;  // 64000*4 floats, 16B aligned

  head_kernel<<<512, 256, 0, stream>>>(feats, proposals, Wc, bc, Wb, bb, out,
                                       ws_scores, ws_boxes);
  nms_kernel<<<kB, 256, 0, stream>>>(ws_scores, ws_boxes, out);
}

// Round 4
// 444.892 us; speedup vs baseline: 1.0575x; 1.0028x over previous
//
#include <hip/hip_runtime.h>
#include <math.h>

#define IMG 800.0f
#define SCORE_TH 0.25f
#define NMS_TH 0.5f
#define MAXDET 100
#define BBOX_CLIP 4.135166556742356f /* log(1000/16) */

constexpr int kB = 16;
constexpr int kN = 4000;
constexpr int kD = 1024;

// ---------------------------------------------------------------------------
// Kernel 1: fused head matmul (6 needed channels only) + softmax + box decode.
// One wave per row; per-lane weight slice held in registers (24 float4).
// BW-bound: 262 MB feats at ~6.6 TB/s ~= 40-42 us floor; 2 waves/SIMD already
// deliver ~23 B/cy/CU issue capacity vs the 10.25 B/cy/CU HBM floor, so no
// prefetch/occupancy games needed (measured: prefetch variant not faster).
// NOTE: single-kernel fusion with a device-scope counter handshake HANGS under
// rocprof dispatch replay (counter not re-zeroed between passes -> consumer
// spins forever). Keep the two-kernel form; the kernel boundary is the sync.
// ---------------------------------------------------------------------------
__global__ __launch_bounds__(256, 2) void head_kernel(
    const float* __restrict__ feats, const float* __restrict__ proposals,
    const float* __restrict__ Wc, const float* __restrict__ bc,
    const float* __restrict__ Wb, const float* __restrict__ bb,
    float* __restrict__ out, float* __restrict__ ws_scores,
    float* __restrict__ ws_boxes) {
  const int lane = threadIdx.x & 63;
  const int waveId = (blockIdx.x * blockDim.x + threadIdx.x) >> 6;
  const int nWaves = (gridDim.x * blockDim.x) >> 6;

  const float4* Wc4 = (const float4*)Wc;  // (2,1024) -> 2*256 float4
  const float4* Wb4 = (const float4*)Wb;  // (8,1024) -> 8*256 float4
  float4 w0[4], w1[4], w4[4], w5[4], w6[4], w7[4];
#pragma unroll
  for (int ch = 0; ch < 4; ++ch) {
    int idx = ch * 64 + lane;
    w0[ch] = Wc4[0 * 256 + idx];
    w1[ch] = Wc4[1 * 256 + idx];
    w4[ch] = Wb4[4 * 256 + idx];
    w5[ch] = Wb4[5 * 256 + idx];
    w6[ch] = Wb4[6 * 256 + idx];
    w7[ch] = Wb4[7 * 256 + idx];
  }
  const float bc0 = bc[0], bc1 = bc[1];
  const float bb4 = bb[4], bb5 = bb[5], bb6 = bb[6], bb7 = bb[7];

  const int R = kB * kN;
  for (int row = waveId; row < R; row += nWaves) {
    const float4* F = (const float4*)(feats + (size_t)row * kD);
    float a0 = 0.f, a1 = 0.f, a4 = 0.f, a5 = 0.f, a6 = 0.f, a7 = 0.f;
#pragma unroll
    for (int ch = 0; ch < 4; ++ch) {
      float4 f = F[ch * 64 + lane];
      a0 = fmaf(f.x, w0[ch].x, fmaf(f.y, w0[ch].y, fmaf(f.z, w0[ch].z, fmaf(f.w, w0[ch].w, a0))));
      a1 = fmaf(f.x, w1[ch].x, fmaf(f.y, w1[ch].y, fmaf(f.z, w1[ch].z, fmaf(f.w, w1[ch].w, a1))));
      a4 = fmaf(f.x, w4[ch].x, fmaf(f.y, w4[ch].y, fmaf(f.z, w4[ch].z, fmaf(f.w, w4[ch].w, a4))));
      a5 = fmaf(f.x, w5[ch].x, fmaf(f.y, w5[ch].y, fmaf(f.z, w5[ch].z, fmaf(f.w, w5[ch].w, a5))));
      a6 = fmaf(f.x, w6[ch].x, fmaf(f.y, w6[ch].y, fmaf(f.z, w6[ch].z, fmaf(f.w, w6[ch].w, a6))));
      a7 = fmaf(f.x, w7[ch].x, fmaf(f.y, w7[ch].y, fmaf(f.z, w7[ch].z, fmaf(f.w, w7[ch].w, a7))));
    }
#pragma unroll
    for (int off = 32; off; off >>= 1) {
      a0 += __shfl_xor(a0, off);
      a1 += __shfl_xor(a1, off);
      a4 += __shfl_xor(a4, off);
      a5 += __shfl_xor(a5, off);
      a6 += __shfl_xor(a6, off);
      a7 += __shfl_xor(a7, off);
    }
    if (lane == 0) {
      float l0 = a0 + bc0, l1 = a1 + bc1;
      float score = 1.0f / (1.0f + __expf(l0 - l1));
      float sth = score > SCORE_TH ? score : 0.0f;

      float4 p = ((const float4*)proposals)[row];
      float w = p.z - p.x, h = p.w - p.y;
      float cx = p.x + 0.5f * w, cy = p.y + 0.5f * h;
      float dx = (a4 + bb4) * 0.1f;
      float dy = (a5 + bb5) * 0.1f;
      float dw = fminf((a6 + bb6) * 0.2f, BBOX_CLIP);
      float dh = fminf((a7 + bb7) * 0.2f, BBOX_CLIP);
      float pcx = fmaf(dx, w, cx), pcy = fmaf(dy, h, cy);
      float pw = __expf(dw) * w, ph = __expf(dh) * h;
      float x1 = fminf(fmaxf(pcx - 0.5f * pw, 0.f), IMG);
      float y1 = fminf(fmaxf(pcy - 0.5f * ph, 0.f), IMG);
      float x2 = fminf(fmaxf(pcx + 0.5f * pw, 0.f), IMG);
      float y2 = fminf(fmaxf(pcy + 0.5f * ph, 0.f), IMG);

      size_t ob = (size_t)row * 5;
      out[ob + 0] = x1;
      out[ob + 1] = y1;
      out[ob + 2] = x2;
      out[ob + 3] = y2;
      ws_scores[row] = sth;
      ((float4*)ws_boxes)[row] = make_float4(x1, y1, x2, y2);
    }
  }
}

// ---------------------------------------------------------------------------
// DPP-based wave argmax on packed u64 keys: VALU-latency cross-lane instead of
// ds_bpermute (~120 cy/stage). Zero-fill (bound_ctrl + old=0) is safe: all
// real keys are > 0, so a 0 candidate never wins.
// ---------------------------------------------------------------------------
template <int CTRL>
__device__ __forceinline__ unsigned long long dpp_max_u64(unsigned long long k) {
  int lo = __builtin_amdgcn_update_dpp(0, (int)(unsigned)k, CTRL, 0xF, 0xF, true);
  int hi =
      __builtin_amdgcn_update_dpp(0, (int)(unsigned)(k >> 32), CTRL, 0xF, 0xF, true);
  unsigned long long o = ((unsigned long long)(unsigned)hi << 32) | (unsigned)lo;
  return o > k ? o : k;
}

__device__ __forceinline__ unsigned long long wave_max_u64(unsigned long long k) {
  k = dpp_max_u64<0x121>(k);  // row_ror:1
  k = dpp_max_u64<0x122>(k);  // row_ror:2
  k = dpp_max_u64<0x124>(k);  // row_ror:4
  k = dpp_max_u64<0x128>(k);  // row_ror:8   (every lane: 16-lane row max)
  k = dpp_max_u64<0x142>(k);  // row_bcast15 (rows 1,3 pick up rows 0,2)
  k = dpp_max_u64<0x143>(k);  // row_bcast31 (lane 63: wave max)
  return k;
}

// ---------------------------------------------------------------------------
// Kernel 2: greedy NMS, one 256-thread block (4 waves) per batch image.
// 4 waves = 1 wave/SIMD is the per-SIMD-issue sweet spot: the IoU work per
// SIMD is invariant under thread-count changes (measured: 1024-thread variant
// regressed +23 us from 4x the DPP chains + wider key tree + 16-wave barrier).
// Chain-bound at ~1150 cy/iter (issue ~600 cy < chain), so further slot
// redistribution cannot help. State per thread (row n = k*256 + t): khi[16] =
// score bits (suppress -> 0), box[16], areaE[16]. Key = (khi << 32) | ~n:
// max-key == reference argmax with first-index tie-break; sentinels (khi=0,
// n>=4000) lose to all real rows; all-suppressed case picks row 0 with
// valid=false (keep-revocation exact). One barrier/iter, double-buffered
// 4-wave leader keys in LDS.
// ---------------------------------------------------------------------------
__global__ __launch_bounds__(256, 1) void nms_kernel(
    const float* __restrict__ ws_scores, const float* __restrict__ ws_boxes,
    float* __restrict__ out) {
  const int b = blockIdx.x;
  const int t = threadIdx.x;  // 0..255
  const int wave = t >> 6;
  const int lane = t & 63;

  __shared__ float4 Lbox[kN];  // 64000 B
  alignas(16) __shared__ unsigned long long Lkey[2][4];

  const float* sc = ws_scores + (size_t)b * kN;
  const float4* bx = (const float4*)ws_boxes + (size_t)b * kN;

  unsigned khi[16];
  float areaE[16];  // area + 1e-9
  float4 box[16];
  unsigned keep_mask = 0u;
  const unsigned nt = ~(unsigned)t;  // ~(0*256+t); slot k low word = nt - 256k

#pragma unroll
  for (int k = 0; k < 16; ++k) {
    int n = k * 256 + t;
    if (n < kN) {
      box[k] = bx[n];
      khi[k] = __float_as_uint(sc[n]);  // scores >= 0: bits monotone
      areaE[k] = fmaxf(box[k].z - box[k].x, 0.f) *
                     fmaxf(box[k].w - box[k].y, 0.f) +
                 1e-9f;
      Lbox[n] = box[k];
    } else {
      box[k] = make_float4(0.f, 0.f, 0.f, 0.f);  // inter==0 vs any real box
      khi[k] = 0u;
      areaE[k] = 1e-9f;
    }
  }

  auto reduce_publish = [&](int parity) {
    unsigned long long lk[16];
#pragma unroll
    for (int k = 0; k < 16; ++k)
      lk[k] = ((unsigned long long)khi[k] << 32) |
              (unsigned long long)(nt - (unsigned)(k * 256));
#pragma unroll
    for (int k = 0; k < 8; ++k) lk[k] = lk[k] > lk[k + 8] ? lk[k] : lk[k + 8];
#pragma unroll
    for (int k = 0; k < 4; ++k) lk[k] = lk[k] > lk[k + 4] ? lk[k] : lk[k + 4];
    lk[0] = lk[0] > lk[2] ? lk[0] : lk[2];
    lk[1] = lk[1] > lk[3] ? lk[1] : lk[3];
    lk[0] = lk[0] > lk[1] ? lk[0] : lk[1];
    unsigned long long wkey = wave_max_u64(lk[0]);
    if (lane == 63) Lkey[parity][wave] = wkey;
  };

  reduce_publish(1);  // loop it=0 reads parity (0+1)&1 = 1
  __syncthreads();

  for (int it = 0; it < MAXDET; ++it) {
    const int pr = (it + 1) & 1;
    // 4 leader keys as 2x ds_read_b128 (16B-aligned), broadcast (conflict-free)
    const ulonglong2* Lk2 = (const ulonglong2*)(&Lkey[pr][0]);
    ulonglong2 p01 = Lk2[0];
    ulonglong2 p23 = Lk2[1];
    unsigned long long wk = p01.x > p01.y ? p01.x : p01.y;
    unsigned long long k2 = p23.x > p23.y ? p23.x : p23.y;
    wk = wk > k2 ? wk : k2;
    // Uniform across the block -> scalarize the decode.
    const unsigned whi = (unsigned)__builtin_amdgcn_readfirstlane((int)(wk >> 32));
    const unsigned wlo = (unsigned)__builtin_amdgcn_readfirstlane((int)(unsigned)wk);
    const unsigned wn = ~wlo;  // winner row, always < kN
    const bool valid = whi != 0u;
    const float4 wb = Lbox[wn];  // broadcast read
    const float wa = fmaxf(wb.z - wb.x, 0.f) * fmaxf(wb.w - wb.y, 0.f);
    const bool iOwn = ((unsigned)t == (wn & 255u));
    const int oSlot = (int)(wn >> 8);
    if (iOwn) {
      unsigned bit = 1u << oSlot;
      keep_mask = valid ? (keep_mask | bit) : (keep_mask & ~bit);
    }
#pragma unroll
    for (int k = 0; k < 16; ++k) {
      float dx = fminf(wb.z, box[k].z) - fmaxf(wb.x, box[k].x);
      float dy = fminf(wb.w, box[k].w) - fmaxf(wb.y, box[k].y);
      float inter3 = 3.0f * fmaxf(dx, 0.f) * fmaxf(dy, 0.f);
      // iou > 0.5  <=>  3*inter > wa + area + 1e-9
      bool sup = inter3 > wa + areaE[k];
      if (sup || (iOwn && k == oSlot)) khi[k] = 0u;
    }
    reduce_publish(it & 1);
    __syncthreads();
  }

#pragma unroll
  for (int k = 0; k < 16; ++k) {
    int n = k * 256 + t;
    if (n < kN) {
      // ws_scores untouched by this kernel: re-read instead of keeping orig[]
      out[((size_t)(b * kN + n)) * 5 + 4] =
          (keep_mask >> k) & 1u ? sc[n] : 0.0f;
    }
  }
}

extern "C" void kernel_launch(void* const* d_in, const int* in_sizes, int n_in,
                              void* d_out, int out_size, void* d_ws,
                              size_t ws_size, hipStream_t stream) {
  const float* feats = (const float*)d_in[0];      // (16,4000,1024)
  const float* proposals = (const float*)d_in[1];  // (16,4000,4)
  const float* Wc = (const float*)d_in[2];         // (2,1024)
  const float* bc = (const float*)d_in[3];         // (2,)
  const float* Wb = (const float*)d_in[4];         // (8,1024)
  const float* bb = (const float*)d_in[5];         // (8,)
  float* out = (float*)d_out;                      // (16,4000,5)

  float* ws_scores = (float*)d_ws;        // 64000 floats
  float* ws_boxes = ws_scores + kB * kN;  // 64000*4 floats, 16B aligned

  head_kernel<<<512, 256, 0, stream>>>(feats, proposals, Wc, bc, Wb, bb, out,
                                       ws_scores, ws_boxes);
  nms_kernel<<<kB, 256, 0, stream>>>(ws_scores, ws_boxes, out);
}